// Round 6
// baseline (753.774 us; speedup 1.0000x reference)
//
#include <hip/hip_runtime.h>
#include <hip/hip_bf16.h>
#include <math.h>

// Problem constants (B=2, S=2048, C=1024, H=16, D=64, Cv=1024)
#define B_    2
#define S_    2048
#define C_    1024
#define H_    16
#define D_    64
#define TWO_C 2048
#define CV    1024
#define K_    1024
#define N_ALL 3072   // Wqk (2048) ++ Wv (1024)
#define GRID  1024   // persistent grid; 4 blocks/CU co-resident (guaranteed)

typedef float  floatx4 __attribute__((ext_vector_type(4)));
typedef short  shortx8 __attribute__((ext_vector_type(8)));
typedef short  shortx4 __attribute__((ext_vector_type(4)));

__device__ __forceinline__ ushort f2bf(float f) {
  unsigned u = __builtin_bit_cast(unsigned, f);
  u += 0x7fff + ((u >> 16) & 1);   // RNE
  return (ushort)(u >> 16);
}

// async global->LDS, 16B per lane; LDS dst = wave-uniform base + lane*16
__device__ __forceinline__ void gl2lds16(const ushort* g, ushort* l) {
  __builtin_amdgcn_global_load_lds(
      (const __attribute__((address_space(1))) unsigned int*)(const void*)g,
      (__attribute__((address_space(3))) unsigned int*)(void*)l, 16, 0, 0);
}

// Device-scope grid barrier (all GRID blocks guaranteed co-resident by
// __launch_bounds__(256,4): VGPR<=128 -> 4 waves/SIMD; LDS 32KB*4 <= 160KB).
// Same algorithm as AMD cooperative-groups grid.sync().
__device__ __forceinline__ void grid_barrier(unsigned* cnt, unsigned target) {
  __syncthreads();
  __threadfence();                       // release: drain stores to device scope
  if (threadIdx.x == 0) {
    __hip_atomic_fetch_add(cnt, 1u, __ATOMIC_RELEASE, __HIP_MEMORY_SCOPE_AGENT);
    while (__hip_atomic_load(cnt, __ATOMIC_ACQUIRE, __HIP_MEMORY_SCOPE_AGENT) < target)
      __builtin_amdgcn_s_sleep(2);
  }
  __syncthreads();
  __threadfence();                       // acquire: invalidate stale caches
}

__global__ __launch_bounds__(256, 4) void fused_all(
    const float* __restrict__ x, const float* __restrict__ Wqk,
    const float* __restrict__ Wv, const float* __restrict__ bqk,
    const float* __restrict__ bv, ushort* __restrict__ xbf,
    ushort* __restrict__ wtbf, ushort* __restrict__ qkbf,
    ushort* __restrict__ vtbf, float* __restrict__ out,
    unsigned* __restrict__ bar) {
  __shared__ __align__(16) char smem[32768];   // union: gemm 32KB / flash 25KB / prep 2.1KB

  const int tx = threadIdx.x;
  const int w = tx >> 6;
  const int lane = tx & 63;
  const int lq = lane & 15;
  const int quad = lane >> 4;

  // ================= phase 0: prep (convert x, transpose weights) =========
  {
    ushort (*tile)[33] = (ushort (*)[33])smem;
    for (int item = blockIdx.x; item < 7168; item += GRID) {
      if (item < 4096) {
        const int i = item * 1024 + tx * 4;
        float4 v = *(const float4*)(x + i);
        shortx4 s;
        s[0] = (short)f2bf(v.x); s[1] = (short)f2bf(v.y);
        s[2] = (short)f2bf(v.z); s[3] = (short)f2bf(v.w);
        *(shortx4*)(xbf + i) = s;
      } else {
        const float* W; ushort* WT; int N, idx;
        if (item < 6144) { W = Wqk; WT = wtbf; N = TWO_C; idx = item - 4096; }
        else { W = Wv; WT = wtbf + (size_t)TWO_C * K_; N = CV; idx = item - 6144; }
        const int nb = N / 32;
        const int n0 = (idx % nb) * 32, k0 = (idx / nb) * 32;
        const int ttx = tx & 31, tty = tx >> 5;   // tty 0..7
#pragma unroll
        for (int i = 0; i < 32; i += 8)
          tile[tty + i][ttx] = f2bf(W[(size_t)(k0 + tty + i) * N + n0 + ttx]);
        __syncthreads();
#pragma unroll
        for (int i = 0; i < 32; i += 8)
          WT[(size_t)(n0 + tty + i) * K_ + k0 + ttx] = tile[ttx][tty + i];
        __syncthreads();   // tile reused next item
      }
    }
  }
  grid_barrier(bar, GRID);

  // ================= phase 1: projection GEMM (bf16 MFMA, BK=64) ==========
  if (blockIdx.x < 768) {
    ushort* As = (ushort*)smem;            // 16 KB
    ushort* Bs = (ushort*)(smem + 16384);  // 16 KB
    const int tile = blockIdx.x;
    const int row0 = (tile / 24) * 128;
    const int col0 = (tile % 24) * 128;
    const int wm = (w & 1) * 64;
    const int wn = (w >> 1) * 64;

    // staging: lane -> row lane>>3, source chunk = (lane&7) ^ row (XOR-8 swizzle)
    const int srow = lane >> 3;
    const int schunk = ((lane & 7) ^ srow) * 8;
    const ushort* ag = xbf  + (size_t)(row0 + srow) * K_ + schunk;
    const ushort* bg = wtbf + (size_t)(col0 + srow) * K_ + schunk;

    floatx4 acc[4][4];
#pragma unroll
    for (int i = 0; i < 4; i++)
#pragma unroll
      for (int j = 0; j < 4; j++) acc[i][j] = (floatx4){0.f, 0.f, 0.f, 0.f};

    for (int k0 = 0; k0 < K_; k0 += 64) {
#pragma unroll
      for (int j = 0; j < 4; j++) {
        const int g = w * 4 + j;
        gl2lds16(ag + (size_t)(g * 8) * K_ + k0, As + g * 512);
        gl2lds16(bg + (size_t)(g * 8) * K_ + k0, Bs + g * 512);
      }
      __syncthreads();

#pragma unroll
      for (int kh = 0; kh < 2; kh++) {
        const int co = ((kh * 4 + quad) ^ (lq & 7)) * 8;
        shortx8 af[4], bf[4];
#pragma unroll
        for (int mi = 0; mi < 4; mi++)
          af[mi] = *(const shortx8*)(As + (wm + mi * 16 + lq) * 64 + co);
#pragma unroll
        for (int ni = 0; ni < 4; ni++)
          bf[ni] = *(const shortx8*)(Bs + (wn + ni * 16 + lq) * 64 + co);
#pragma unroll
        for (int mi = 0; mi < 4; mi++)
#pragma unroll
          for (int ni = 0; ni < 4; ni++)
            acc[mi][ni] = __builtin_amdgcn_mfma_f32_16x16x32_bf16(
                af[mi], bf[ni], acc[mi][ni], 0, 0, 0);
      }
      __syncthreads();
    }

    if (col0 < TWO_C) {
#pragma unroll
      for (int mi = 0; mi < 4; mi++) {
        const int m0 = row0 + wm + mi * 16 + quad * 4;
#pragma unroll
        for (int ni = 0; ni < 4; ni++) {
          const int n = col0 + wn + ni * 16 + lq;
          const float bs = bqk[n];
          const float sc = (n < C_) ? 0.125f : 1.0f;
#pragma unroll
          for (int r = 0; r < 4; r++)
            qkbf[(size_t)(m0 + r) * TWO_C + n] = f2bf((acc[mi][ni][r] + bs) * sc);
        }
      }
    } else {
#pragma unroll
      for (int mi = 0; mi < 4; mi++) {
        const int m0 = row0 + wm + mi * 16 + quad * 4;
        const int b = m0 >> 11, s = m0 & (S_ - 1);
#pragma unroll
        for (int ni = 0; ni < 4; ni++) {
          const int n = col0 - TWO_C + wn + ni * 16 + lq;
          const float bs = bv[n];
          shortx4 st;
#pragma unroll
          for (int r = 0; r < 4; r++) st[r] = (short)f2bf(acc[mi][ni][r] + bs);
          *(shortx4*)(vtbf + ((size_t)((b << 4) | (n >> 6)) * 64 + (n & 63)) * S_ + s) = st;
        }
      }
    }
  }
  grid_barrier(bar, 2 * GRID);

  // ================= phase 2: flash attention ==============================
  {
    ushort* Ks = (ushort*)smem;            // 8 KB: K tile [64 key][64 d]
    ushort* Vs = (ushort*)(smem + 8192);   // 8 KB: V^T tile [64 d][64 key]
    ushort* Ps = (ushort*)(smem + 16384);  // 9 KB: per-wave P^T

    // complementary qtile mapping: the 4 blocks {b, b+256, b+512, b+768}
    // (one per CU slot) get qtiles {t, 15-t, 16+t, 31-t} -> 66 k-iters/CU const
    const int half = blockIdx.x >> 8;
    const int r8 = blockIdx.x & 255;
    const int t4 = r8 & 15, u4 = r8 >> 4;
    const int qtile = ((half & 2) << 3) | ((half & 1) ? (15 - t4) : t4);
    const int bh = ((half & 1) << 4) | u4;
    const int b = bh >> 4, h = bh & 15;
    const int q0 = qtile * 64;
    const int qloc = w * 16 + lq;
    const int qg = q0 + qloc;

    const ushort* qbase = qkbf + (size_t)(b * S_ + qg) * TWO_C + h * D_;
    const shortx8 qf0 = *(const shortx8*)(qbase + quad * 8);
    const shortx8 qf1 = *(const shortx8*)(qbase + 32 + quad * 8);

    const ushort* kbase = qkbf + (size_t)b * S_ * TWO_C + C_ + h * D_;
    const ushort* vbase = vtbf + (size_t)(b * H_ + h) * D_ * S_;

    const int kk = lane >> 3, oo = lane & 7;
    const int oswz = (oo ^ kk) * 8;
    const ushort* ksrc = kbase + (size_t)(w * 16 + kk) * TWO_C + oswz;
    const ushort* vsrc = vbase + (size_t)(w * 16 + kk) * S_ + oswz;
    ushort* kdst0 = Ks + (2 * w) * 512;
    ushort* kdst1 = Ks + (2 * w + 1) * 512;
    ushort* vdst0 = Vs + (2 * w) * 512;
    ushort* vdst1 = Vs + (2 * w + 1) * 512;

    const int xo0 = ((0 * 4 + quad) ^ (lq & 7)) * 8;
    const int xo1 = ((1 * 4 + quad) ^ (lq & 7)) * 8;

    floatx4 o[4];
#pragma unroll
    for (int i = 0; i < 4; i++) o[i] = (floatx4){0.f, 0.f, 0.f, 0.f};
    float l = 0.f;
    ushort* Pw = Ps + w * (16 * 72);

    const int nkt = qtile + 1;
    for (int t = 0; t < nkt; t++) {
      const size_t k0 = (size_t)t * 64;
      gl2lds16(ksrc + k0 * TWO_C,               kdst0);
      gl2lds16(ksrc + k0 * TWO_C + 8 * TWO_C,   kdst1);
      gl2lds16(vsrc + k0,                       vdst0);
      gl2lds16(vsrc + k0 + 8 * S_,              vdst1);
      __syncthreads();

      floatx4 sa[4];
#pragma unroll
      for (int s = 0; s < 4; s++) {
        const int rb = (s * 16 + lq) * 64;
        const shortx8 kf0 = *(const shortx8*)(Ks + rb + xo0);
        const shortx8 kf1 = *(const shortx8*)(Ks + rb + xo1);
        floatx4 a = {0.f, 0.f, 0.f, 0.f};
        a = __builtin_amdgcn_mfma_f32_16x16x32_bf16(kf0, qf0, a, 0, 0, 0);
        a = __builtin_amdgcn_mfma_f32_16x16x32_bf16(kf1, qf1, a, 0, 0, 0);
        sa[s] = a;
      }

      if (t == qtile) {
#pragma unroll
        for (int s = 0; s < 4; s++)
#pragma unroll
          for (int r = 0; r < 4; r++)
            if (s * 16 + quad * 4 + r > qloc) sa[s][r] = -1e30f;
      }

      float psum = 0.f;
#pragma unroll
      for (int s = 0; s < 4; s++) {
        shortx4 pw;
#pragma unroll
        for (int r = 0; r < 4; r++) {
          float p = __expf(sa[s][r]);
          psum += p;
          pw[r] = (short)f2bf(p);
        }
        *(shortx4*)(Pw + lq * 72 + s * 16 + quad * 4) = pw;
      }
      l += psum;
      __asm__ __volatile__("s_waitcnt lgkmcnt(0)" ::: "memory");

      const shortx8 pf0 = *(const shortx8*)(Pw + lq * 72 + quad * 8);
      const shortx8 pf1 = *(const shortx8*)(Pw + lq * 72 + 32 + quad * 8);

#pragma unroll
      for (int ds = 0; ds < 4; ds++) {
        const int rb = (ds * 16 + lq) * 64;
        const shortx8 vf0 = *(const shortx8*)(Vs + rb + xo0);
        const shortx8 vf1 = *(const shortx8*)(Vs + rb + xo1);
        o[ds] = __builtin_amdgcn_mfma_f32_16x16x32_bf16(vf0, pf0, o[ds], 0, 0, 0);
        o[ds] = __builtin_amdgcn_mfma_f32_16x16x32_bf16(vf1, pf1, o[ds], 0, 0, 0);
      }
      __syncthreads();
    }

    l += __shfl_xor(l, 16, 64);
    l += __shfl_xor(l, 32, 64);
    const float inv = 1.0f / l;

    float* op = out + (size_t)(b * S_ + qg) * CV + h * D_ + quad * 4;
    *(floatx4*)(op + 0)  = o[0] * inv;
    *(floatx4*)(op + 16) = o[1] * inv;
    *(floatx4*)(op + 32) = o[2] * inv;
    *(floatx4*)(op + 48) = o[3] * inv;
  }
}

extern "C" void kernel_launch(void* const* d_in, const int* in_sizes, int n_in,
                              void* d_out, int out_size, void* d_ws, size_t ws_size,
                              hipStream_t stream) {
  const float* x   = (const float*)d_in[0];
  const float* Wqk = (const float*)d_in[1];
  const float* bqk = (const float*)d_in[2];
  const float* Wv  = (const float*)d_in[3];
  const float* bv  = (const float*)d_in[4];
  float* out = (float*)d_out;

  // Workspace (ushorts): qk [4096][2048] | V^T [2048][2048] | xbf [4096][1024]
  //                      | wtbf [3072][1024] | barrier counter (64 B)
  ushort* qkbf = (ushort*)d_ws;
  ushort* vtbf = qkbf + (size_t)(B_ * S_) * TWO_C;
  ushort* xbf  = vtbf + (size_t)TWO_C * S_;
  ushort* wtbf = xbf  + (size_t)(B_ * S_) * K_;
  unsigned* bar = (unsigned*)(wtbf + (size_t)N_ALL * K_);

  hipMemsetAsync((void*)bar, 0, 64, stream);
  fused_all<<<dim3(GRID), dim3(256), 0, stream>>>(
      x, Wqk, Wv, bqk, bv, xbf, wtbf, qkbf, vtbf, out, bar);
}

// Round 7
// 159.476 us; speedup vs baseline: 4.7266x; 4.7266x over previous
//
#include <hip/hip_runtime.h>
#include <hip/hip_bf16.h>
#include <math.h>

// Problem constants (B=2, S=2048, C=1024, H=16, D=64, Cv=1024)
#define B_    2
#define S_    2048
#define C_    1024
#define H_    16
#define D_    64
#define TWO_C 2048
#define CV    1024
#define K_    1024
#define N_ALL 3072   // Wqk (2048) ++ Wv (1024)

typedef float  floatx4 __attribute__((ext_vector_type(4)));
typedef short  shortx8 __attribute__((ext_vector_type(8)));
typedef short  shortx4 __attribute__((ext_vector_type(4)));

__device__ __forceinline__ ushort f2bf(float f) {
  unsigned u = __builtin_bit_cast(unsigned, f);
  u += 0x7fff + ((u >> 16) & 1);   // RNE
  return (ushort)(u >> 16);
}

// async global->LDS, 16B per lane; LDS dst = wave-uniform base + lane*16
__device__ __forceinline__ void gl2lds16(const ushort* g, ushort* l) {
  __builtin_amdgcn_global_load_lds(
      (const __attribute__((address_space(1))) unsigned int*)(const void*)g,
      (__attribute__((address_space(3))) unsigned int*)(void*)l, 16, 0, 0);
}

// ---------------- prep: convert x -> bf16, transpose Wqk/Wv -> WT bf16 -----
//   [0, 4096):        x fp32 [4096][1024] -> xbf (row-major)
//   [4096, 6144):     Wqk [1024][2048] -> wtbf[0..2048) rows [N][K]
//   [6144, 7168):     Wv  [1024][1024] -> wtbf[2048..3072) rows
__global__ __launch_bounds__(256) void prep_kernel(
    const float* __restrict__ x, const float* __restrict__ Wqk,
    const float* __restrict__ Wv, ushort* __restrict__ xbf,
    ushort* __restrict__ wtbf) {
  const int blk = blockIdx.x;
  if (blk < 4096) {
    const int i = blk * 1024 + threadIdx.x * 4;
    float4 v = *(const float4*)(x + i);
    shortx4 s;
    s[0] = (short)f2bf(v.x); s[1] = (short)f2bf(v.y);
    s[2] = (short)f2bf(v.z); s[3] = (short)f2bf(v.w);
    *(shortx4*)(xbf + i) = s;
    return;
  }
  __shared__ ushort tile[32][33];
  const float* W; ushort* WT; int N, idx;
  if (blk < 6144) { W = Wqk; WT = wtbf; N = TWO_C; idx = blk - 4096; }
  else { W = Wv; WT = wtbf + (size_t)TWO_C * K_; N = CV; idx = blk - 6144; }
  const int nb = N / 32;
  const int n0 = (idx % nb) * 32, k0 = (idx / nb) * 32;
  const int tx = threadIdx.x & 31, ty = threadIdx.x >> 5;   // ty 0..7
#pragma unroll
  for (int i = 0; i < 32; i += 8)
    tile[ty + i][tx] = f2bf(W[(size_t)(k0 + ty + i) * N + n0 + tx]);
  __syncthreads();
#pragma unroll
  for (int i = 0; i < 32; i += 8)
    WT[(size_t)(n0 + ty + i) * K_ + k0 + tx] = tile[tx][ty + i];
}

// ---------------- fused projection GEMM (bf16 MFMA, BK=64, XOR-8 swizzle) --
// A = xbf [4096][1024], BT = wtbf [3072][1024] (rows K-contiguous).
// 128x128 tile, BK=64 (16 iters, 32 MFMAs/barrier).
// Block mapping: blockIdx.x = ROW tile (fastest) so the 8 consecutive blocks
// round-robined onto the 8 XCDs share one B col-tile (L2 reuse of B),
// while A row-tiles stream distinct per XCD.
// LDS rows are 128B = 8 chunks of 16B; chunk c of row r lives at physical
// chunk c ^ (r&7) (swizzle applied at DMA source) -> 0 bank conflicts.
__global__ __launch_bounds__(256) void gemm_mfma(
    const ushort* __restrict__ A, const ushort* __restrict__ BT,
    const float* __restrict__ bqk, const float* __restrict__ bv,
    ushort* __restrict__ qkout, ushort* __restrict__ vtout) {
  __shared__ __align__(16) ushort As[128 * 64];   // 16 KB
  __shared__ __align__(16) ushort Bs[128 * 64];   // 16 KB

  const int tx = threadIdx.x;
  const int w = tx >> 6;
  const int lane = tx & 63;
  const int lq = lane & 15;
  const int quad = lane >> 4;
  const int row0 = blockIdx.x * 128;   // row fastest (XCD round-robin shares B)
  const int col0 = blockIdx.y * 128;
  const int wm = (w & 1) * 64;
  const int wn = (w >> 1) * 64;

  // staging: lane -> row lane>>3, source chunk = (lane&7) ^ row (XOR-8 swizzle)
  const int srow = lane >> 3;
  const int schunk = ((lane & 7) ^ srow) * 8;
  const ushort* ag = A  + (size_t)(row0 + srow) * K_ + schunk;
  const ushort* bg = BT + (size_t)(col0 + srow) * K_ + schunk;

  floatx4 acc[4][4];
#pragma unroll
  for (int i = 0; i < 4; i++)
#pragma unroll
    for (int j = 0; j < 4; j++) acc[i][j] = (floatx4){0.f, 0.f, 0.f, 0.f};

  for (int k0 = 0; k0 < K_; k0 += 64) {
#pragma unroll
    for (int j = 0; j < 4; j++) {
      const int g = w * 4 + j;
      gl2lds16(ag + (size_t)(g * 8) * K_ + k0, As + g * 512);
      gl2lds16(bg + (size_t)(g * 8) * K_ + k0, Bs + g * 512);
    }
    __syncthreads();   // drains DMA (vmcnt) + lds

#pragma unroll
    for (int kh = 0; kh < 2; kh++) {
      const int co = ((kh * 4 + quad) ^ (lq & 7)) * 8;   // swizzled chunk offset
      shortx8 af[4], bf[4];
#pragma unroll
      for (int mi = 0; mi < 4; mi++)
        af[mi] = *(const shortx8*)(As + (wm + mi * 16 + lq) * 64 + co);
#pragma unroll
      for (int ni = 0; ni < 4; ni++)
        bf[ni] = *(const shortx8*)(Bs + (wn + ni * 16 + lq) * 64 + co);
#pragma unroll
      for (int mi = 0; mi < 4; mi++)
#pragma unroll
        for (int ni = 0; ni < 4; ni++)
          acc[mi][ni] = __builtin_amdgcn_mfma_f32_16x16x32_bf16(
              af[mi], bf[ni], acc[mi][ni], 0, 0, 0);
    }
    __syncthreads();
  }

  if (col0 < TWO_C) {
#pragma unroll
    for (int mi = 0; mi < 4; mi++) {
      const int m0 = row0 + wm + mi * 16 + quad * 4;
#pragma unroll
      for (int ni = 0; ni < 4; ni++) {
        const int n = col0 + wn + ni * 16 + lq;
        const float bs = bqk[n];
        const float sc = (n < C_) ? 0.125f : 1.0f;
#pragma unroll
        for (int r = 0; r < 4; r++)
          qkout[(size_t)(m0 + r) * TWO_C + n] = f2bf((acc[mi][ni][r] + bs) * sc);
      }
    }
  } else {
#pragma unroll
    for (int mi = 0; mi < 4; mi++) {
      const int m0 = row0 + wm + mi * 16 + quad * 4;
      const int b = m0 >> 11, s = m0 & (S_ - 1);
#pragma unroll
      for (int ni = 0; ni < 4; ni++) {
        const int n = col0 - TWO_C + wn + ni * 16 + lq;
        const float bs = bv[n];
        shortx4 st;
#pragma unroll
        for (int r = 0; r < 4; r++) st[r] = (short)f2bf(acc[mi][ni][r] + bs);
        *(shortx4*)(vtout + ((size_t)((b << 4) | (n >> 6)) * 64 + (n & 63)) * S_ + s) = st;
      }
    }
  }
}

// ---------------- Flash attention v2 (R4/R5 known-good) --------------------
__global__ __launch_bounds__(256, 4) void flash_attn(
    const ushort* __restrict__ qk, const ushort* __restrict__ vt,
    float* __restrict__ out) {
  __shared__ __align__(16) ushort Ks[64 * 64];     // 8 KB
  __shared__ __align__(16) ushort Vs[64 * 64];     // 8 KB
  __shared__ __align__(16) ushort Ps[4][16 * 72];  // 9 KB

  const int w = threadIdx.x >> 6;
  const int lane = threadIdx.x & 63;
  const int lq = lane & 15;
  const int quad = lane >> 4;

  const int bh = blockIdx.x & 31;
  const int qtile = 31 - (blockIdx.x >> 5);  // heavy tiles first
  const int b = bh >> 4, h = bh & 15;
  const int q0 = qtile * 64;
  const int qloc = w * 16 + lq;
  const int qg = q0 + qloc;

  const ushort* qbase = qk + (size_t)(b * S_ + qg) * TWO_C + h * D_;
  const shortx8 qf0 = *(const shortx8*)(qbase + quad * 8);
  const shortx8 qf1 = *(const shortx8*)(qbase + 32 + quad * 8);

  const ushort* kbase = qk + (size_t)b * S_ * TWO_C + C_ + h * D_;
  const ushort* vbase = vt + (size_t)(b * H_ + h) * D_ * S_;

  const int kk = lane >> 3, oo = lane & 7;
  const int oswz = (oo ^ kk) * 8;
  const ushort* ksrc = kbase + (size_t)(w * 16 + kk) * TWO_C + oswz;
  const ushort* vsrc = vbase + (size_t)(w * 16 + kk) * S_ + oswz;
  ushort* kdst0 = Ks + (2 * w) * 512;
  ushort* kdst1 = Ks + (2 * w + 1) * 512;
  ushort* vdst0 = Vs + (2 * w) * 512;
  ushort* vdst1 = Vs + (2 * w + 1) * 512;

  const int xo0 = ((0 * 4 + quad) ^ (lq & 7)) * 8;
  const int xo1 = ((1 * 4 + quad) ^ (lq & 7)) * 8;

  floatx4 o[4];
#pragma unroll
  for (int i = 0; i < 4; i++) o[i] = (floatx4){0.f, 0.f, 0.f, 0.f};
  float l = 0.f;
  ushort* Pw = Ps[w];

  const int nkt = qtile + 1;
  for (int t = 0; t < nkt; t++) {
    const size_t k0 = (size_t)t * 64;
    gl2lds16(ksrc + k0 * TWO_C,               kdst0);
    gl2lds16(ksrc + k0 * TWO_C + 8 * TWO_C,   kdst1);
    gl2lds16(vsrc + k0,                       vdst0);
    gl2lds16(vsrc + k0 + 8 * S_,              vdst1);
    __syncthreads();

    floatx4 sa[4];
#pragma unroll
    for (int s = 0; s < 4; s++) {
      const int rb = (s * 16 + lq) * 64;
      const shortx8 kf0 = *(const shortx8*)(Ks + rb + xo0);
      const shortx8 kf1 = *(const shortx8*)(Ks + rb + xo1);
      floatx4 a = {0.f, 0.f, 0.f, 0.f};
      a = __builtin_amdgcn_mfma_f32_16x16x32_bf16(kf0, qf0, a, 0, 0, 0);
      a = __builtin_amdgcn_mfma_f32_16x16x32_bf16(kf1, qf1, a, 0, 0, 0);
      sa[s] = a;
    }

    if (t == qtile) {
#pragma unroll
      for (int s = 0; s < 4; s++)
#pragma unroll
        for (int r = 0; r < 4; r++)
          if (s * 16 + quad * 4 + r > qloc) sa[s][r] = -1e30f;
    }

    float psum = 0.f;
#pragma unroll
    for (int s = 0; s < 4; s++) {
      shortx4 pw;
#pragma unroll
      for (int r = 0; r < 4; r++) {
        float p = __expf(sa[s][r]);
        psum += p;
        pw[r] = (short)f2bf(p);
      }
      *(shortx4*)(Pw + lq * 72 + s * 16 + quad * 4) = pw;
    }
    l += psum;
    __asm__ __volatile__("s_waitcnt lgkmcnt(0)" ::: "memory");

    const shortx8 pf0 = *(const shortx8*)(Pw + lq * 72 + quad * 8);
    const shortx8 pf1 = *(const shortx8*)(Pw + lq * 72 + 32 + quad * 8);

#pragma unroll
    for (int ds = 0; ds < 4; ds++) {
      const int rb = (ds * 16 + lq) * 64;
      const shortx8 vf0 = *(const shortx8*)(Vs + rb + xo0);
      const shortx8 vf1 = *(const shortx8*)(Vs + rb + xo1);
      o[ds] = __builtin_amdgcn_mfma_f32_16x16x32_bf16(vf0, pf0, o[ds], 0, 0, 0);
      o[ds] = __builtin_amdgcn_mfma_f32_16x16x32_bf16(vf1, pf1, o[ds], 0, 0, 0);
    }
    __syncthreads();
  }

  l += __shfl_xor(l, 16, 64);
  l += __shfl_xor(l, 32, 64);
  const float inv = 1.0f / l;

  float* op = out + (size_t)(b * S_ + qg) * CV + h * D_ + quad * 4;
  *(floatx4*)(op + 0)  = o[0] * inv;
  *(floatx4*)(op + 16) = o[1] * inv;
  *(floatx4*)(op + 32) = o[2] * inv;
  *(floatx4*)(op + 48) = o[3] * inv;
}

extern "C" void kernel_launch(void* const* d_in, const int* in_sizes, int n_in,
                              void* d_out, int out_size, void* d_ws, size_t ws_size,
                              hipStream_t stream) {
  const float* x   = (const float*)d_in[0];
  const float* Wqk = (const float*)d_in[1];
  const float* bqk = (const float*)d_in[2];
  const float* Wv  = (const float*)d_in[3];
  const float* bv  = (const float*)d_in[4];
  float* out = (float*)d_out;

  // Workspace (ushorts): qk [4096][2048] | V^T [2048][2048] | xbf [4096][1024]
  //                      | wtbf [3072][1024]   => ~39.8 MB total
  ushort* qkbf = (ushort*)d_ws;
  ushort* vtbf = qkbf + (size_t)(B_ * S_) * TWO_C;
  ushort* xbf  = vtbf + (size_t)TWO_C * S_;
  ushort* wtbf = xbf  + (size_t)(B_ * S_) * K_;

  dim3 blk(256);
  prep_kernel<<<dim3(4096 + 2048 + 1024), blk, 0, stream>>>(x, Wqk, Wv, xbf, wtbf);
  gemm_mfma<<<dim3((B_ * S_) / 128, N_ALL / 128), blk, 0, stream>>>(
      xbf, wtbf, bqk, bv, qkbf, vtbf);
  flash_attn<<<dim3(32 * 32), blk, 0, stream>>>(qkbf, vtbf, out);
}